// Round 3
// baseline (30523.099 us; speedup 1.0000x reference)
//
#include <hip/hip_runtime.h>
#include <hip/hip_bf16.h>
#include <stdint.h>

// ---------------------------------------------------------------------------
// Bidirectional 5-layer LSTM (all-sigmoid), B=16, T=1024, D=1024, U=512.
// R3: kill the h-exchange LDS round trip + barrier count.
//   - producers store h directly in MFMA A-fragment layout to a global abuf
//     (aliases the dead ycur buffer); consumers load A-frags straight to
//     registers via coalesced agent-scope loads. No LDS h staging.
//   - per-WAVE flags (64/dir): each wave polls all 64 with __all ballot and
//     releases its own flag; no barrier around poll/flag.
//   - double-buffered padded zbuf/xbuf -> ONE __syncthreads per step.
//   - MFMA: 4 independent accumulator chains (k-split) to halve chain latency.
// ---------------------------------------------------------------------------

typedef __attribute__((ext_vector_type(8))) short short8;
typedef __attribute__((ext_vector_type(4))) float f32x4;

union U128 { uint4 u; short8 s; };
static __device__ __forceinline__ short8 as_short8(uint4 v) { U128 x; x.u = v; return x.s; }
union U64x2 { unsigned long long q[2]; short8 s; };

static __device__ __forceinline__ float sigf(float x) { return 1.0f / (1.0f + __expf(-x)); }

static __device__ __forceinline__ uint32_t f2bfbits(float f) {
  union { float f; uint32_t u; } x; x.f = f;
  return (x.u + 0x7fffu + ((x.u >> 16) & 1u)) >> 16;   // RNE; h in (0,1), no NaN
}
static __device__ __forceinline__ float bflo(uint32_t v) {
  union { uint32_t u; float f; } x; x.u = v << 16; return x.f;
}
static __device__ __forceinline__ float bfhi(uint32_t v) {
  union { uint32_t u; float f; } x; x.u = v & 0xffff0000u; return x.f;
}

// ---------------- x (fp32) -> bf16 ----------------
__global__ __launch_bounds__(256) void f32_to_bf16_k(const float* __restrict__ in,
                                                     __hip_bfloat16* __restrict__ out,
                                                     int n4) {
  int i = blockIdx.x * 256 + threadIdx.x;
  if (i < n4) {
    float4 v = ((const float4*)in)[i];
    uint32_t lo = f2bfbits(v.x) | (f2bfbits(v.y) << 16);
    uint32_t hi = f2bfbits(v.z) | (f2bfbits(v.w) << 16);
    ((uint2*)out)[i] = make_uint2(lo, hi);
  }
}

// ---------------- [2][R][2048] fp32 -> [2][2048][R] bf16 transpose ----------------
__global__ __launch_bounds__(256) void transpose_bf16_k(const float* __restrict__ in,
                                                        __hip_bfloat16* __restrict__ outp,
                                                        int R) {
  __shared__ float tile[64][65];
  int d = blockIdx.z;
  int k0 = blockIdx.x * 64;
  int c0 = blockIdx.y * 64;
  const float* inb = in + (size_t)d * R * 2048;
  __hip_bfloat16* ob = outp + (size_t)d * 2048 * R;
  int col = threadIdx.x & 63, rr = threadIdx.x >> 6;
#pragma unroll
  for (int i = 0; i < 16; ++i) {
    int r = rr + i * 4;
    tile[r][col] = inb[(size_t)(k0 + r) * 2048 + c0 + col];
  }
  __syncthreads();
#pragma unroll
  for (int i = 0; i < 16; ++i) {
    int r = rr + i * 4;
    ob[(size_t)(c0 + r) * R + k0 + col] = __float2bfloat16(tile[col][r]);
  }
}

// ---------------- xz GEMM: y[16384,1024] @ Wt[2][2048,1024]^T + b ----------------
// Output layout: xz[dir][swg(16)][t(1024)][gate(4)][b(16)][j(32)]  (4KB chunks)
__global__ __launch_bounds__(256) void gemm_xz_k(const __hip_bfloat16* __restrict__ y,
                                                 const __hip_bfloat16* __restrict__ Wt,
                                                 const float* __restrict__ bias,
                                                 __hip_bfloat16* __restrict__ xz) {
  __shared__ uint4 Asl[8 * 2 * 64];
  __shared__ uint4 Bsl[8 * 2 * 64];
  int m0 = blockIdx.x * 128;
  int dir = blockIdx.y >> 4;
  int n0 = (blockIdx.y & 15) * 128;
  int tid = threadIdx.x, lane = tid & 63, wv = tid >> 6;
  int wm = wv & 1, wn = wv >> 1;
  const __hip_bfloat16* Wd = Wt + (size_t)dir * 2048 * 1024;
  f32x4 acc[4][4] = {};
  for (int kb = 0; kb < 1024; kb += 64) {
    __syncthreads();
#pragma unroll
    for (int i = 0; i < 4; ++i) {
      int slot = i * 256 + tid;
      int ln = slot & 63, kc = (slot >> 6) & 1, mt = slot >> 7;
      int row = mt * 16 + (ln & 15);
      int kk = kc * 32 + (ln >> 4) * 8;
      Asl[slot] = *(const uint4*)(y + (size_t)(m0 + row) * 1024 + kb + kk);
      Bsl[slot] = *(const uint4*)(Wd + (size_t)(n0 + row) * 1024 + kb + kk);
    }
    __syncthreads();
#pragma unroll
    for (int kc = 0; kc < 2; ++kc) {
      short8 af[4], bf[4];
#pragma unroll
      for (int i = 0; i < 4; ++i) {
        af[i] = as_short8(Asl[((wm * 4 + i) * 2 + kc) * 64 + lane]);
        bf[i] = as_short8(Bsl[((wn * 4 + i) * 2 + kc) * 64 + lane]);
      }
#pragma unroll
      for (int i = 0; i < 4; ++i)
#pragma unroll
        for (int j = 0; j < 4; ++j)
          acc[i][j] = __builtin_amdgcn_mfma_f32_16x16x32_bf16(af[i], bf[j], acc[i][j], 0, 0, 0);
    }
  }
  int cq = lane >> 4, cn = lane & 15;
#pragma unroll
  for (int i = 0; i < 4; ++i)
#pragma unroll
    for (int j = 0; j < 4; ++j) {
      int n_g = n0 + (wn * 4 + j) * 16 + cn;
      int q = n_g >> 9, u = n_g & 511, swg = u >> 5, jj = u & 31;
      float bv = bias[dir * 2048 + n_g];
#pragma unroll
      for (int r = 0; r < 4; ++r) {
        int m = m0 + (wm * 4 + i) * 16 + cq * 4 + r;
        int b = m >> 10, t = m & 1023;
        size_t addr = (((size_t)(dir * 16 + swg) * 1024 + t) * 2048) + (q * 16 + b) * 32 + jj;
        xz[addr] = __float2bfloat16(acc[i][j][r] + bv);
      }
    }
}

// ---------------- persistent bidirectional recurrence ----------------
// 32 blocks: dir = blockIdx&1, slice swg = blockIdx>>1 (32 u-cols each).
// abuf[dir][t][1024 slots x 16B]: slot kc*64+lane = h[b=lane&15][u=kc*32+(lane>>4)*8+j]
// LDS: uh 128KB | zbuf 2x16x129 f32 (16512B) | xbuf 2x2048 bf16 (8192B) = 155776B
__global__ __launch_bounds__(256) void lstm_rec_k(const __hip_bfloat16* __restrict__ Ut,   // [2][2048][512]
                                                  const __hip_bfloat16* __restrict__ xz,   // [dir][swg][t][2048]
                                                  __hip_bfloat16* __restrict__ abuf,       // [2][1024][8192]
                                                  __hip_bfloat16* __restrict__ ynext,      // [16][1024][1024]
                                                  float* __restrict__ outf,                // last layer or null
                                                  int* __restrict__ arrive) {              // [2][64 slots x 16]
  extern __shared__ char smem[];
  uint4* uh = (uint4*)smem;                                   // 8192 x 16B
  float* zbuf = (float*)(smem + 131072);                      // [2][16][129]
  __hip_bfloat16* xbuf = (__hip_bfloat16*)(smem + 147584);    // [2][2048]
  int dir = blockIdx.x & 1;
  int swg = blockIdx.x >> 1;
  int u0 = swg * 32;
  int tid = threadIdx.x, lane = tid & 63, wv = tid >> 6;
  int quad = lane >> 4, l15 = lane & 15;
  const __hip_bfloat16* Ud = Ut + (size_t)dir * 2048 * 512;

  // Uh slice -> LDS, pre-fragmented (B-operand layout)
#pragma unroll 4
  for (int i = 0; i < 32; ++i) {
    int slot = i * 256 + tid;
    int ls = slot & 63, kc = (slot >> 6) & 15, nt = slot >> 10;
    int n_g = (nt >> 1) * 512 + u0 + (nt & 1) * 16 + (ls & 15);
    int k = kc * 32 + (ls >> 4) * 8;
    uh[slot] = *(const uint4*)(Ud + (size_t)n_g * 512 + k);
  }
  __syncthreads();

  int nt0 = wv * 2, nt1 = wv * 2 + 1;
  int pb = tid >> 4, pj = (tid & 15) * 2;
  float c0 = 0.f, c1 = 0.f;
  int* flag = arrive + dir * 1024;                    // 64 slots, 64B apart
  const int* fp = flag + lane * 16;                   // this lane's poll target
  int myslot = (swg * 4 + wv) * 16;
  const __hip_bfloat16* xzb = xz + (size_t)(dir * 16 + swg) * 1024 * 2048;
  __hip_bfloat16* ab_d = abuf + (size_t)dir * 1024 * 8192;
  // producer target: slot = swg*64 + (pj>>3)*16 + pb, byte elem = slot*8 + (pj&7)
  int pelem = (swg * 64 + (pj >> 3) * 16 + pb) * 8 + (pj & 7);

  uint4 xcur = *((const uint4*)(xzb + (size_t)(dir ? 1023 : 0) * 2048) + tid);

  for (int s = 0; s < 1024; ++s) {
    int t = dir ? (1023 - s) : s;
    uint4 xnxt;
    if (s < 1023)
      xnxt = *((const uint4*)(xzb + (size_t)(dir ? 1022 - s : s + 1) * 2048) + tid);

    f32x4 zA0 = {}, zB0 = {}, zA1 = {}, zB1 = {};
    if (s > 0) {
      int tprev = dir ? (t + 1) : (t - 1);
      // per-wave autonomous poll of all 64 producer-wave flags
      for (;;) {
        int v = __hip_atomic_load(fp, __ATOMIC_RELAXED, __HIP_MEMORY_SCOPE_AGENT);
        if (__all(v >= s)) break;
      }
      // A-fragments straight from global (coalesced 8B agent loads)
      const unsigned long long* hb = (const unsigned long long*)(ab_d + (size_t)tprev * 8192);
      unsigned long long a[32];
#pragma unroll
      for (int kc = 0; kc < 16; ++kc) {
        const unsigned long long* p = hb + (size_t)(kc * 64 + lane) * 2;
        a[2 * kc]     = __hip_atomic_load(p,     __ATOMIC_RELAXED, __HIP_MEMORY_SCOPE_AGENT);
        a[2 * kc + 1] = __hip_atomic_load(p + 1, __ATOMIC_RELAXED, __HIP_MEMORY_SCOPE_AGENT);
      }
      // 4 independent MFMA chains (k-split per n-tile)
#pragma unroll
      for (int kc = 0; kc < 8; ++kc) {
        U64x2 u0f, u1f;
        u0f.q[0] = a[2 * kc];     u0f.q[1] = a[2 * kc + 1];
        u1f.q[0] = a[2 * kc + 16]; u1f.q[1] = a[2 * kc + 17];
        zA0 = __builtin_amdgcn_mfma_f32_16x16x32_bf16(u0f.s, as_short8(uh[(nt0 * 16 + kc) * 64 + lane]), zA0, 0, 0, 0);
        zA1 = __builtin_amdgcn_mfma_f32_16x16x32_bf16(u0f.s, as_short8(uh[(nt1 * 16 + kc) * 64 + lane]), zA1, 0, 0, 0);
        zB0 = __builtin_amdgcn_mfma_f32_16x16x32_bf16(u1f.s, as_short8(uh[(nt0 * 16 + kc + 8) * 64 + lane]), zB0, 0, 0, 0);
        zB1 = __builtin_amdgcn_mfma_f32_16x16x32_bf16(u1f.s, as_short8(uh[(nt1 * 16 + kc + 8) * 64 + lane]), zB1, 0, 0, 0);
      }
    }
    // publish z (padded, double-buffered) + stage xz chunk
    int half = s & 1;
    float* zw = zbuf + half * 2064;
#pragma unroll
    for (int r = 0; r < 4; ++r) {
      int m = quad * 4 + r;
      zw[m * 129 + nt0 * 16 + l15] = zA0[r] + zB0[r];
      zw[m * 129 + nt1 * 16 + l15] = zA1[r] + zB1[r];
    }
    *(uint4*)(xbuf + half * 2048 + tid * 8) = xcur;
    __syncthreads();   // the ONE barrier per step
    // gates: i,f,g,o = sigmoid; c = f*c + i*g; h = o*sigmoid(c)
    const float* zb = zbuf + half * 2064 + pb * 129;
    const __hip_bfloat16* xr = xbuf + half * 2048;
    uint32_t xi = *(const uint32_t*)(xr + (0 * 16 + pb) * 32 + pj);
    uint32_t xf = *(const uint32_t*)(xr + (1 * 16 + pb) * 32 + pj);
    uint32_t xg = *(const uint32_t*)(xr + (2 * 16 + pb) * 32 + pj);
    uint32_t xo = *(const uint32_t*)(xr + (3 * 16 + pb) * 32 + pj);
    float2 zi = *(const float2*)(zb + pj);
    float2 zf = *(const float2*)(zb + 32 + pj);
    float2 zg = *(const float2*)(zb + 64 + pj);
    float2 zo = *(const float2*)(zb + 96 + pj);
    float i0 = sigf(zi.x + bflo(xi)), i1 = sigf(zi.y + bfhi(xi));
    float f0 = sigf(zf.x + bflo(xf)), f1 = sigf(zf.y + bfhi(xf));
    float g0 = sigf(zg.x + bflo(xg)), g1 = sigf(zg.y + bfhi(xg));
    float o0 = sigf(zo.x + bflo(xo)), o1 = sigf(zo.y + bfhi(xo));
    c0 = f0 * c0 + i0 * g0;
    c1 = f1 * c1 + i1 * g1;
    float h0 = o0 * sigf(c0);
    float h1 = o1 * sigf(c1);
    uint32_t hp = f2bfbits(h0) | (f2bfbits(h1) << 16);
    // h -> abuf in A-fragment layout (the only latency-critical store)
    __hip_atomic_store((uint32_t*)(ab_d + (size_t)t * 8192 + pelem), hp,
                       __ATOMIC_RELAXED, __HIP_MEMORY_SCOPE_AGENT);
    size_t oidx = ((size_t)pb * 1024 + t) * 1024 + dir * 512 + u0 + pj;
    if (outf) {
      union { float f[2]; unsigned long long q; } hv; hv.f[0] = h0; hv.f[1] = h1;
      __hip_atomic_store((unsigned long long*)(outf + oidx), hv.q,
                         __ATOMIC_RELAXED, __HIP_MEMORY_SCOPE_AGENT);
    } else {
      __hip_atomic_store((uint32_t*)(ynext + oidx), hp,
                         __ATOMIC_RELAXED, __HIP_MEMORY_SCOPE_AGENT);
    }
    if (lane == 0)   // per-wave release: orders this wave's stores before flag
      __hip_atomic_store(flag + myslot, s + 1, __ATOMIC_RELEASE, __HIP_MEMORY_SCOPE_AGENT);
    xcur = xnxt;
  }
}

// ---------------------------------------------------------------------------
extern "C" void kernel_launch(void* const* d_in, const int* in_sizes, int n_in,
                              void* d_out, int out_size, void* d_ws, size_t ws_size,
                              hipStream_t stream) {
  const float* x  = (const float*)d_in[0];   // [16][1024][1024]
  const float* W  = (const float*)d_in[1];   // [5][2][1024][2048]
  const float* Uh = (const float*)d_in[2];   // [5][2][512][2048]
  const float* b  = (const float*)d_in[3];   // [5][2][2048]

  char* ws = (char*)d_ws;
  size_t off = 0;
  __hip_bfloat16* yA = (__hip_bfloat16*)(ws + off); off += (size_t)16 * 1024 * 1024 * 2;
  __hip_bfloat16* yB = (__hip_bfloat16*)(ws + off); off += (size_t)16 * 1024 * 1024 * 2;
  __hip_bfloat16* xz = (__hip_bfloat16*)(ws + off); off += (size_t)2 * 16 * 1024 * 2048 * 2;
  __hip_bfloat16* Wt = (__hip_bfloat16*)(ws + off); off += (size_t)2 * 2048 * 1024 * 2;
  __hip_bfloat16* Ut = (__hip_bfloat16*)(ws + off); off += (size_t)2 * 2048 * 512 * 2;
  int* flags = (int*)(ws + off); off += (size_t)5 * 2048 * 4;   // per layer: 2 dirs x 64 slots x 64B

  hipMemsetAsync(flags, 0, 5 * 2048 * sizeof(int), stream);
  f32_to_bf16_k<<<dim3(16384), dim3(256), 0, stream>>>(x, yA, 4194304);
  hipFuncSetAttribute(reinterpret_cast<const void*>(lstm_rec_k),
                      hipFuncAttributeMaxDynamicSharedMemorySize, 155776);
  for (int l = 0; l < 5; ++l) {
    transpose_bf16_k<<<dim3(16, 32, 2), dim3(256), 0, stream>>>(W + (size_t)l * 2 * 1024 * 2048, Wt, 1024);
    transpose_bf16_k<<<dim3(8, 32, 2),  dim3(256), 0, stream>>>(Uh + (size_t)l * 2 * 512 * 2048, Ut, 512);
    __hip_bfloat16* ycur = (l & 1) ? yB : yA;
    __hip_bfloat16* ynxt = (l & 1) ? yA : yB;
    gemm_xz_k<<<dim3(128, 32), dim3(256), 0, stream>>>(ycur, Wt, b + (size_t)l * 2 * 2048, xz);
    // abuf aliases ycur: GEMM is done with it; rec scribbles h-fragments there.
    lstm_rec_k<<<dim3(32), dim3(256), 155776, stream>>>(
        Ut, xz, ycur, ynxt, (l == 4) ? (float*)d_out : nullptr, flags + l * 2048);
  }
}